// Round 1
// baseline (286.166 us; speedup 1.0000x reference)
//
#include <hip/hip_runtime.h>

#define RESOLUTION 0.05f

__global__ __launch_bounds__(256) void octree_sdf_kernel(
    const float* __restrict__ points,        // [P,3]
    const int*   __restrict__ voxel_indices, // [P]
    const float* __restrict__ voxel_centers, // [V,3]
    const int*   __restrict__ vertex_indices,// [V,8]
    const int*   __restrict__ voxel_sizes,   // [V]
    const float* __restrict__ sdf_priors,    // [V]
    const float* __restrict__ grad_priors,   // [V,3]
    float* __restrict__ out_sdf,             // [P]
    float* __restrict__ out_idx,             // [P] (indices as float)
    int n)
{
    int i = blockIdx.x * blockDim.x + threadIdx.x;
    if (i >= n) return;

    float px = points[3*i + 0];
    float py = points[3*i + 1];
    float pz = points[3*i + 2];

    int v = voxel_indices[i];

    float cx = voxel_centers[3*v + 0];
    float cy = voxel_centers[3*v + 1];
    float cz = voxel_centers[3*v + 2];

    float size = (float)voxel_sizes[v] * RESOLUTION;

    // local trilinear coords, exact division to match reference numerics
    float tx = (px - cx) / size + 0.5f;
    float ty = (py - cy) / size + 0.5f;
    float tz = (pz - cz) / size + 0.5f;

    // 8 vertex ids: two int4 loads (32B aligned since v*8*4)
    const int4* vi4 = (const int4*)(vertex_indices + 8*v);
    int4 va = vi4[0];
    int4 vb = vi4[1];
    int vid[8] = {va.x, va.y, va.z, va.w, vb.x, vb.y, vb.z, vb.w};

    float half_size = 0.5f * size;
    float sdf = 0.0f;

    #pragma unroll
    for (int k = 0; k < 8; ++k) {
        float bx = (float)( k       & 1);
        float by = (float)((k >> 1) & 1);
        float bz = (float)((k >> 2) & 1);

        float w = (bx > 0.0f ? tx : 1.0f - tx)
                * (by > 0.0f ? ty : 1.0f - ty)
                * (bz > 0.0f ? tz : 1.0f - tz);

        int u = vid[k];
        float val = sdf_priors[u];
        float gx  = grad_priors[3*u + 0];
        float gy  = grad_priors[3*u + 1];
        float gz  = grad_priors[3*u + 2];

        // corner = center + (bits-0.5)*size ; delta = point - corner
        float dx = px - (cx + (2.0f*bx - 1.0f) * half_size);
        float dy = py - (cy + (2.0f*by - 1.0f) * half_size);
        float dz = pz - (cz + (2.0f*bz - 1.0f) * half_size);

        sdf += w * (val + gx*dx + gy*dy + gz*dz);
    }

    out_sdf[i] = sdf;
    out_idx[i] = (float)v;   // harness reads d_out as f32; idx < 2^24 exact
}

extern "C" void kernel_launch(void* const* d_in, const int* in_sizes, int n_in,
                              void* d_out, int out_size, void* d_ws, size_t ws_size,
                              hipStream_t stream) {
    const float* points         = (const float*)d_in[0];
    const int*   voxel_indices  = (const int*)  d_in[1];
    const float* voxel_centers  = (const float*)d_in[2];
    const int*   vertex_indices = (const int*)  d_in[3];
    const int*   voxel_sizes    = (const int*)  d_in[4];
    const float* sdf_priors     = (const float*)d_in[5];
    const float* grad_priors    = (const float*)d_in[6];

    int n = in_sizes[1];              // number of points
    float* out_sdf = (float*)d_out;
    float* out_idx = out_sdf + n;

    int block = 256;
    int grid  = (n + block - 1) / block;
    octree_sdf_kernel<<<grid, block, 0, stream>>>(
        points, voxel_indices, voxel_centers, vertex_indices,
        voxel_sizes, sdf_priors, grad_priors, out_sdf, out_idx, n);
}

// Round 2
// 208.036 us; speedup vs baseline: 1.3756x; 1.3756x over previous
//
#include <hip/hip_runtime.h>

#define RESOLUTION 0.05f

// Pre-pass: pack gathered tables into 16B-aligned float4 records so every
// random gather in the main kernel touches exactly one cache line.
//   vdata[v] = {sdf_priors[v], grad_priors[3v+0..2]}
//   vmeta[v] = {cx, cy, cz, size_in_world_units}
__global__ __launch_bounds__(256) void pack_tables_kernel(
    const float* __restrict__ voxel_centers,
    const int*   __restrict__ voxel_sizes,
    const float* __restrict__ sdf_priors,
    const float* __restrict__ grad_priors,
    float4* __restrict__ vmeta,
    float4* __restrict__ vdata,
    int V)
{
    int v = blockIdx.x * blockDim.x + threadIdx.x;
    if (v >= V) return;

    float4 m;
    m.x = voxel_centers[3*v + 0];
    m.y = voxel_centers[3*v + 1];
    m.z = voxel_centers[3*v + 2];
    m.w = (float)voxel_sizes[v] * RESOLUTION;
    vmeta[v] = m;

    float4 d;
    d.x = sdf_priors[v];
    d.y = grad_priors[3*v + 0];
    d.z = grad_priors[3*v + 1];
    d.w = grad_priors[3*v + 2];
    vdata[v] = d;
}

__global__ __launch_bounds__(256) void octree_sdf_packed_kernel(
    const float*  __restrict__ points,        // [P,3]
    const int*    __restrict__ voxel_indices, // [P]
    const int*    __restrict__ vertex_indices,// [V,8]
    const float4* __restrict__ vmeta,         // [V] {cx,cy,cz,size}
    const float4* __restrict__ vdata,         // [V] {sdf,gx,gy,gz}
    float* __restrict__ out_sdf,              // [P]
    float* __restrict__ out_idx,              // [P]
    int n)
{
    int i = blockIdx.x * blockDim.x + threadIdx.x;
    if (i >= n) return;

    float px = points[3*i + 0];
    float py = points[3*i + 1];
    float pz = points[3*i + 2];

    int v = voxel_indices[i];

    // 8 vertex ids: two int4 loads (32B-aligned, single 64B line)
    const int4* vi4 = (const int4*)(vertex_indices + 8*v);
    int4 va = vi4[0];
    int4 vb = vi4[1];
    int vid[8] = {va.x, va.y, va.z, va.w, vb.x, vb.y, vb.z, vb.w};

    float4 m = vmeta[v];
    float cx = m.x, cy = m.y, cz = m.z;
    float size = m.w;

    // issue all 8 independent corner gathers up front (MLP)
    float4 cd[8];
    #pragma unroll
    for (int k = 0; k < 8; ++k) cd[k] = vdata[vid[k]];

    float tx = (px - cx) / size + 0.5f;
    float ty = (py - cy) / size + 0.5f;
    float tz = (pz - cz) / size + 0.5f;

    float half_size = 0.5f * size;
    float sdf = 0.0f;

    #pragma unroll
    for (int k = 0; k < 8; ++k) {
        float bx = (float)( k       & 1);
        float by = (float)((k >> 1) & 1);
        float bz = (float)((k >> 2) & 1);

        float w = (bx > 0.0f ? tx : 1.0f - tx)
                * (by > 0.0f ? ty : 1.0f - ty)
                * (bz > 0.0f ? tz : 1.0f - tz);

        float dx = px - (cx + (2.0f*bx - 1.0f) * half_size);
        float dy = py - (cy + (2.0f*by - 1.0f) * half_size);
        float dz = pz - (cz + (2.0f*bz - 1.0f) * half_size);

        sdf += w * (cd[k].x + cd[k].y*dx + cd[k].z*dy + cd[k].w*dz);
    }

    out_sdf[i] = sdf;
    out_idx[i] = (float)v;
}

// Fallback (unpacked) kernel in case ws_size is too small to hold the packed
// tables — identical math to round-1 kernel.
__global__ __launch_bounds__(256) void octree_sdf_kernel(
    const float* __restrict__ points,
    const int*   __restrict__ voxel_indices,
    const float* __restrict__ voxel_centers,
    const int*   __restrict__ vertex_indices,
    const int*   __restrict__ voxel_sizes,
    const float* __restrict__ sdf_priors,
    const float* __restrict__ grad_priors,
    float* __restrict__ out_sdf,
    float* __restrict__ out_idx,
    int n)
{
    int i = blockIdx.x * blockDim.x + threadIdx.x;
    if (i >= n) return;

    float px = points[3*i + 0];
    float py = points[3*i + 1];
    float pz = points[3*i + 2];

    int v = voxel_indices[i];

    float cx = voxel_centers[3*v + 0];
    float cy = voxel_centers[3*v + 1];
    float cz = voxel_centers[3*v + 2];
    float size = (float)voxel_sizes[v] * RESOLUTION;

    float tx = (px - cx) / size + 0.5f;
    float ty = (py - cy) / size + 0.5f;
    float tz = (pz - cz) / size + 0.5f;

    const int4* vi4 = (const int4*)(vertex_indices + 8*v);
    int4 va = vi4[0];
    int4 vb = vi4[1];
    int vid[8] = {va.x, va.y, va.z, va.w, vb.x, vb.y, vb.z, vb.w};

    float half_size = 0.5f * size;
    float sdf = 0.0f;

    #pragma unroll
    for (int k = 0; k < 8; ++k) {
        float bx = (float)( k       & 1);
        float by = (float)((k >> 1) & 1);
        float bz = (float)((k >> 2) & 1);

        float w = (bx > 0.0f ? tx : 1.0f - tx)
                * (by > 0.0f ? ty : 1.0f - ty)
                * (bz > 0.0f ? tz : 1.0f - tz);

        int u = vid[k];
        float val = sdf_priors[u];
        float gx  = grad_priors[3*u + 0];
        float gy  = grad_priors[3*u + 1];
        float gz  = grad_priors[3*u + 2];

        float dx = px - (cx + (2.0f*bx - 1.0f) * half_size);
        float dy = py - (cy + (2.0f*by - 1.0f) * half_size);
        float dz = pz - (cz + (2.0f*bz - 1.0f) * half_size);

        sdf += w * (val + gx*dx + gy*dy + gz*dz);
    }

    out_sdf[i] = sdf;
    out_idx[i] = (float)v;
}

extern "C" void kernel_launch(void* const* d_in, const int* in_sizes, int n_in,
                              void* d_out, int out_size, void* d_ws, size_t ws_size,
                              hipStream_t stream) {
    const float* points         = (const float*)d_in[0];
    const int*   voxel_indices  = (const int*)  d_in[1];
    const float* voxel_centers  = (const float*)d_in[2];
    const int*   vertex_indices = (const int*)  d_in[3];
    const int*   voxel_sizes    = (const int*)  d_in[4];
    const float* sdf_priors     = (const float*)d_in[5];
    const float* grad_priors    = (const float*)d_in[6];

    int n = in_sizes[1];  // points
    int V = in_sizes[4];  // voxels
    float* out_sdf = (float*)d_out;
    float* out_idx = out_sdf + n;

    int block = 256;
    size_t need = (size_t)V * 16 * 2;

    if (ws_size >= need) {
        float4* vmeta = (float4*)d_ws;
        float4* vdata = vmeta + V;

        pack_tables_kernel<<<(V + block - 1) / block, block, 0, stream>>>(
            voxel_centers, voxel_sizes, sdf_priors, grad_priors, vmeta, vdata, V);

        octree_sdf_packed_kernel<<<(n + block - 1) / block, block, 0, stream>>>(
            points, voxel_indices, vertex_indices, vmeta, vdata,
            out_sdf, out_idx, n);
    } else {
        octree_sdf_kernel<<<(n + block - 1) / block, block, 0, stream>>>(
            points, voxel_indices, voxel_centers, vertex_indices,
            voxel_sizes, sdf_priors, grad_priors, out_sdf, out_idx, n);
    }
}

// Round 3
// 164.604 us; speedup vs baseline: 1.7385x; 1.2639x over previous
//
#include <hip/hip_runtime.h>

#define RESOLUTION 0.05f

// ---------- stage 1: pack per-voxel meta and per-vertex data into float4 ----------
//   vmeta[v] = {cx, cy, cz, size_world}
//   vdata[v] = {sdf, gx, gy, gz}
__global__ __launch_bounds__(256) void pack_tables_kernel(
    const float* __restrict__ voxel_centers,
    const int*   __restrict__ voxel_sizes,
    const float* __restrict__ sdf_priors,
    const float* __restrict__ grad_priors,
    float4* __restrict__ vmeta,
    float4* __restrict__ vdata,
    int V)
{
    int v = blockIdx.x * blockDim.x + threadIdx.x;
    if (v >= V) return;

    float4 m;
    m.x = voxel_centers[3*v + 0];
    m.y = voxel_centers[3*v + 1];
    m.z = voxel_centers[3*v + 2];
    m.w = (float)voxel_sizes[v] * RESOLUTION;
    vmeta[v] = m;

    float4 d;
    d.x = sdf_priors[v];
    d.y = grad_priors[3*v + 0];
    d.z = grad_priors[3*v + 1];
    d.w = grad_priors[3*v + 2];
    vdata[v] = d;
}

// ---------- stage 2: per-voxel corner records (128 B, 64 B-aligned) ----------
// corner k record: {A_k, Bx_k, By_k, Bz_k} with
//   B_k = size * grad_k
//   A_k = sdf_k - (Bx*bx + By*by + Bz*bz)    (since delta = size*(t - bits))
// so per point:  sdf = sum_k w_k(t) * (A_k + Bx*tx + By*ty + Bz*tz)
__global__ __launch_bounds__(256) void pack_corners_kernel(
    const int*    __restrict__ vertex_indices, // [V,8]
    const float4* __restrict__ vmeta,          // [V]
    const float4* __restrict__ vdata,          // [V]
    float4* __restrict__ corners,              // [V,8]
    int V)
{
    int v = blockIdx.x * blockDim.x + threadIdx.x;
    if (v >= V) return;

    const int4* vi4 = (const int4*)(vertex_indices + 8*v);
    int4 va = vi4[0];
    int4 vb = vi4[1];
    int vid[8] = {va.x, va.y, va.z, va.w, vb.x, vb.y, vb.z, vb.w};

    float size = vmeta[v].w;

    float4 rec[8];
    #pragma unroll
    for (int k = 0; k < 8; ++k) {
        float4 d = vdata[vid[k]];
        float bx = (float)( k       & 1);
        float by = (float)((k >> 1) & 1);
        float bz = (float)((k >> 2) & 1);
        float4 r;
        r.y = size * d.y;
        r.z = size * d.z;
        r.w = size * d.w;
        r.x = d.x - (r.y*bx + r.z*by + r.w*bz);
        rec[k] = r;
    }
    float4* out = corners + 8*v;
    #pragma unroll
    for (int k = 0; k < 8; ++k) out[k] = rec[k];
}

// ---------- main: 3 gather lines per point ----------
__global__ __launch_bounds__(256) void octree_sdf_rec_kernel(
    const float*  __restrict__ points,        // [P,3]
    const int*    __restrict__ voxel_indices, // [P]
    const float4* __restrict__ vmeta,         // [V]
    const float4* __restrict__ corners,       // [V,8]
    float* __restrict__ out_sdf,
    float* __restrict__ out_idx,
    int n)
{
    int i = blockIdx.x * blockDim.x + threadIdx.x;
    if (i >= n) return;

    float px = points[3*i + 0];
    float py = points[3*i + 1];
    float pz = points[3*i + 2];

    int v = voxel_indices[i];

    float4 m = vmeta[v];

    // issue the 8 contiguous record loads (2 cache lines) up front
    const float4* cr = corners + 8*v;
    float4 c0 = cr[0], c1 = cr[1], c2 = cr[2], c3 = cr[3];
    float4 c4 = cr[4], c5 = cr[5], c6 = cr[6], c7 = cr[7];

    float tx = (px - m.x) / m.w + 0.5f;
    float ty = (py - m.y) / m.w + 0.5f;
    float tz = (pz - m.z) / m.w + 0.5f;
    float ux = 1.0f - tx, uy = 1.0f - ty, uz = 1.0f - tz;

    float sdf = 0.0f;
    sdf += (ux*uy*uz) * (c0.x + c0.y*tx + c0.z*ty + c0.w*tz);
    sdf += (tx*uy*uz) * (c1.x + c1.y*tx + c1.z*ty + c1.w*tz);
    sdf += (ux*ty*uz) * (c2.x + c2.y*tx + c2.z*ty + c2.w*tz);
    sdf += (tx*ty*uz) * (c3.x + c3.y*tx + c3.z*ty + c3.w*tz);
    sdf += (ux*uy*tz) * (c4.x + c4.y*tx + c4.z*ty + c4.w*tz);
    sdf += (tx*uy*tz) * (c5.x + c5.y*tx + c5.z*ty + c5.w*tz);
    sdf += (ux*ty*tz) * (c6.x + c6.y*tx + c6.z*ty + c6.w*tz);
    sdf += (tx*ty*tz) * (c7.x + c7.y*tx + c7.z*ty + c7.w*tz);

    out_sdf[i] = sdf;
    out_idx[i] = (float)v;
}

// ---------- fallback: round-2 packed kernel (ws too small for corner table) ----------
__global__ __launch_bounds__(256) void octree_sdf_packed_kernel(
    const float*  __restrict__ points,
    const int*    __restrict__ voxel_indices,
    const int*    __restrict__ vertex_indices,
    const float4* __restrict__ vmeta,
    const float4* __restrict__ vdata,
    float* __restrict__ out_sdf,
    float* __restrict__ out_idx,
    int n)
{
    int i = blockIdx.x * blockDim.x + threadIdx.x;
    if (i >= n) return;

    float px = points[3*i + 0];
    float py = points[3*i + 1];
    float pz = points[3*i + 2];

    int v = voxel_indices[i];

    const int4* vi4 = (const int4*)(vertex_indices + 8*v);
    int4 va = vi4[0];
    int4 vb = vi4[1];
    int vid[8] = {va.x, va.y, va.z, va.w, vb.x, vb.y, vb.z, vb.w};

    float4 m = vmeta[v];
    float cx = m.x, cy = m.y, cz = m.z;
    float size = m.w;

    float4 cd[8];
    #pragma unroll
    for (int k = 0; k < 8; ++k) cd[k] = vdata[vid[k]];

    float tx = (px - cx) / size + 0.5f;
    float ty = (py - cy) / size + 0.5f;
    float tz = (pz - cz) / size + 0.5f;

    float half_size = 0.5f * size;
    float sdf = 0.0f;

    #pragma unroll
    for (int k = 0; k < 8; ++k) {
        float bx = (float)( k       & 1);
        float by = (float)((k >> 1) & 1);
        float bz = (float)((k >> 2) & 1);

        float w = (bx > 0.0f ? tx : 1.0f - tx)
                * (by > 0.0f ? ty : 1.0f - ty)
                * (bz > 0.0f ? tz : 1.0f - tz);

        float dx = px - (cx + (2.0f*bx - 1.0f) * half_size);
        float dy = py - (cy + (2.0f*by - 1.0f) * half_size);
        float dz = pz - (cz + (2.0f*bz - 1.0f) * half_size);

        sdf += w * (cd[k].x + cd[k].y*dx + cd[k].z*dy + cd[k].w*dz);
    }

    out_sdf[i] = sdf;
    out_idx[i] = (float)v;
}

extern "C" void kernel_launch(void* const* d_in, const int* in_sizes, int n_in,
                              void* d_out, int out_size, void* d_ws, size_t ws_size,
                              hipStream_t stream) {
    const float* points         = (const float*)d_in[0];
    const int*   voxel_indices  = (const int*)  d_in[1];
    const float* voxel_centers  = (const float*)d_in[2];
    const int*   vertex_indices = (const int*)  d_in[3];
    const int*   voxel_sizes    = (const int*)  d_in[4];
    const float* sdf_priors     = (const float*)d_in[5];
    const float* grad_priors    = (const float*)d_in[6];

    int n = in_sizes[1];  // points
    int V = in_sizes[4];  // voxels
    float* out_sdf = (float*)d_out;
    float* out_idx = out_sdf + n;

    int block = 256;
    int gridV = (V + block - 1) / block;
    int gridP = (n + block - 1) / block;

    size_t need_full   = (size_t)V * (16 + 16 + 128); // vmeta + vdata + corners
    size_t need_packed = (size_t)V * (16 + 16);

    if (ws_size >= need_full) {
        float4* vmeta   = (float4*)d_ws;
        float4* vdata   = vmeta + V;
        float4* corners = vdata + V;   // [V,8], 128B records, 64B-aligned

        pack_tables_kernel<<<gridV, block, 0, stream>>>(
            voxel_centers, voxel_sizes, sdf_priors, grad_priors, vmeta, vdata, V);
        pack_corners_kernel<<<gridV, block, 0, stream>>>(
            vertex_indices, vmeta, vdata, corners, V);
        octree_sdf_rec_kernel<<<gridP, block, 0, stream>>>(
            points, voxel_indices, vmeta, corners, out_sdf, out_idx, n);
    } else if (ws_size >= need_packed) {
        float4* vmeta = (float4*)d_ws;
        float4* vdata = vmeta + V;

        pack_tables_kernel<<<gridV, block, 0, stream>>>(
            voxel_centers, voxel_sizes, sdf_priors, grad_priors, vmeta, vdata, V);
        octree_sdf_packed_kernel<<<gridP, block, 0, stream>>>(
            points, voxel_indices, vertex_indices, vmeta, vdata,
            out_sdf, out_idx, n);
    }
}

// Round 4
// 159.291 us; speedup vs baseline: 1.7965x; 1.0334x over previous
//
#include <hip/hip_runtime.h>
#include <hip/hip_fp16.h>

#define RESOLUTION 0.05f

__device__ __forceinline__ unsigned int pack_h2(float a, float b) {
    __half2 h = __floats2half2_rn(a, b);
    union { __half2 h2; unsigned int ui; } cv; cv.h2 = h;
    return cv.ui;
}
__device__ __forceinline__ float2 unpack_h2(unsigned int u) {
    union { unsigned int ui; __half2 h2; } cv; cv.ui = u;
    return __half22float2(cv.h2);
}

// ---------- single pre-pass ----------
// vmeta[v]   = {cx, cy, cz, size_world}                    (float4, 16B)
// corners[v] = 8 x {A, Bx, By, Bz} in fp16                 (64B = ONE cache line)
//   B_k = size * grad_k ;  A_k = sdf_k - (Bx*bx + By*by + Bz*bz)
//   so per point:  sdf = sum_k w_k(t) * (A_k + Bx*tx + By*ty + Bz*tz)
__global__ __launch_bounds__(256) void pack_kernel(
    const float* __restrict__ voxel_centers,
    const int*   __restrict__ voxel_sizes,
    const float* __restrict__ sdf_priors,
    const float* __restrict__ grad_priors,
    const int*   __restrict__ vertex_indices, // [V,8]
    float4* __restrict__ vmeta,
    uint4*  __restrict__ corners,             // [V*4] (4 x uint4 = 64B per voxel)
    int V)
{
    int v = blockIdx.x * blockDim.x + threadIdx.x;
    if (v >= V) return;

    float size = (float)voxel_sizes[v] * RESOLUTION;

    float4 m;
    m.x = voxel_centers[3*v + 0];
    m.y = voxel_centers[3*v + 1];
    m.z = voxel_centers[3*v + 2];
    m.w = size;
    vmeta[v] = m;

    const int4* vi4 = (const int4*)(vertex_indices + 8*v);
    int4 va = vi4[0];
    int4 vb = vi4[1];
    int vid[8] = {va.x, va.y, va.z, va.w, vb.x, vb.y, vb.z, vb.w};

    unsigned int words[16];
    #pragma unroll
    for (int k = 0; k < 8; ++k) {
        int u = vid[k];
        float s  = sdf_priors[u];
        float Bx = size * grad_priors[3*u + 0];
        float By = size * grad_priors[3*u + 1];
        float Bz = size * grad_priors[3*u + 2];
        float bx = (float)( k       & 1);
        float by = (float)((k >> 1) & 1);
        float bz = (float)((k >> 2) & 1);
        float A  = s - (Bx*bx + By*by + Bz*bz);
        words[2*k + 0] = pack_h2(A,  Bx);
        words[2*k + 1] = pack_h2(By, Bz);
    }

    uint4* out = corners + 4*v;
    #pragma unroll
    for (int q = 0; q < 4; ++q)
        out[q] = make_uint4(words[4*q+0], words[4*q+1], words[4*q+2], words[4*q+3]);
}

// ---------- main: 2 gather lines per point (1 cold) ----------
__global__ __launch_bounds__(256) void octree_sdf_h16_kernel(
    const float*  __restrict__ points,        // [P,3]
    const int*    __restrict__ voxel_indices, // [P]
    const float4* __restrict__ vmeta,         // [V]
    const uint4*  __restrict__ corners,       // [V*4]
    float* __restrict__ out_sdf,
    float* __restrict__ out_idx,
    int n)
{
    int i = blockIdx.x * blockDim.x + threadIdx.x;
    if (i >= n) return;

    float px = points[3*i + 0];
    float py = points[3*i + 1];
    float pz = points[3*i + 2];

    int v = voxel_indices[i];

    float4 m = vmeta[v];

    const uint4* cr = corners + 4*v;
    uint4 q0 = cr[0], q1 = cr[1], q2 = cr[2], q3 = cr[3];
    unsigned int w_[16] = {q0.x,q0.y,q0.z,q0.w, q1.x,q1.y,q1.z,q1.w,
                           q2.x,q2.y,q2.z,q2.w, q3.x,q3.y,q3.z,q3.w};

    float tx = (px - m.x) / m.w + 0.5f;
    float ty = (py - m.y) / m.w + 0.5f;
    float tz = (pz - m.z) / m.w + 0.5f;
    float ux = 1.0f - tx, uy = 1.0f - ty, uz = 1.0f - tz;

    float wt[8] = { ux*uy*uz, tx*uy*uz, ux*ty*uz, tx*ty*uz,
                    ux*uy*tz, tx*uy*tz, ux*ty*tz, tx*ty*tz };

    float sdf = 0.0f;
    #pragma unroll
    for (int k = 0; k < 8; ++k) {
        float2 ab = unpack_h2(w_[2*k + 0]);   // (A,  Bx)
        float2 cd = unpack_h2(w_[2*k + 1]);   // (By, Bz)
        sdf += wt[k] * (ab.x + ab.y*tx + cd.x*ty + cd.y*tz);
    }

    out_sdf[i] = sdf;
    out_idx[i] = (float)v;
}

// ---------- fallback: direct kernel (no workspace needed) ----------
__global__ __launch_bounds__(256) void octree_sdf_direct_kernel(
    const float* __restrict__ points,
    const int*   __restrict__ voxel_indices,
    const float* __restrict__ voxel_centers,
    const int*   __restrict__ vertex_indices,
    const int*   __restrict__ voxel_sizes,
    const float* __restrict__ sdf_priors,
    const float* __restrict__ grad_priors,
    float* __restrict__ out_sdf,
    float* __restrict__ out_idx,
    int n)
{
    int i = blockIdx.x * blockDim.x + threadIdx.x;
    if (i >= n) return;

    float px = points[3*i + 0];
    float py = points[3*i + 1];
    float pz = points[3*i + 2];

    int v = voxel_indices[i];

    float cx = voxel_centers[3*v + 0];
    float cy = voxel_centers[3*v + 1];
    float cz = voxel_centers[3*v + 2];
    float size = (float)voxel_sizes[v] * RESOLUTION;

    float tx = (px - cx) / size + 0.5f;
    float ty = (py - cy) / size + 0.5f;
    float tz = (pz - cz) / size + 0.5f;

    const int4* vi4 = (const int4*)(vertex_indices + 8*v);
    int4 va = vi4[0];
    int4 vb = vi4[1];
    int vid[8] = {va.x, va.y, va.z, va.w, vb.x, vb.y, vb.z, vb.w};

    float half_size = 0.5f * size;
    float sdf = 0.0f;

    #pragma unroll
    for (int k = 0; k < 8; ++k) {
        float bx = (float)( k       & 1);
        float by = (float)((k >> 1) & 1);
        float bz = (float)((k >> 2) & 1);

        float w = (bx > 0.0f ? tx : 1.0f - tx)
                * (by > 0.0f ? ty : 1.0f - ty)
                * (bz > 0.0f ? tz : 1.0f - tz);

        int u = vid[k];
        float val = sdf_priors[u];
        float gx  = grad_priors[3*u + 0];
        float gy  = grad_priors[3*u + 1];
        float gz  = grad_priors[3*u + 2];

        float dx = px - (cx + (2.0f*bx - 1.0f) * half_size);
        float dy = py - (cy + (2.0f*by - 1.0f) * half_size);
        float dz = pz - (cz + (2.0f*bz - 1.0f) * half_size);

        sdf += w * (val + gx*dx + gy*dy + gz*dz);
    }

    out_sdf[i] = sdf;
    out_idx[i] = (float)v;
}

extern "C" void kernel_launch(void* const* d_in, const int* in_sizes, int n_in,
                              void* d_out, int out_size, void* d_ws, size_t ws_size,
                              hipStream_t stream) {
    const float* points         = (const float*)d_in[0];
    const int*   voxel_indices  = (const int*)  d_in[1];
    const float* voxel_centers  = (const float*)d_in[2];
    const int*   vertex_indices = (const int*)  d_in[3];
    const int*   voxel_sizes    = (const int*)  d_in[4];
    const float* sdf_priors     = (const float*)d_in[5];
    const float* grad_priors    = (const float*)d_in[6];

    int n = in_sizes[1];  // points
    int V = in_sizes[4];  // voxels
    float* out_sdf = (float*)d_out;
    float* out_idx = out_sdf + n;

    int block = 256;
    int gridV = (V + block - 1) / block;
    int gridP = (n + block - 1) / block;

    size_t need = (size_t)V * (16 + 64);  // vmeta + fp16 corner records

    if (ws_size >= need) {
        float4* vmeta   = (float4*)d_ws;
        uint4*  corners = (uint4*)(vmeta + V);   // 64B/voxel, 64B-aligned (V*16 % 64 handled below)
        // ensure 64B alignment of corners: V*16 is a multiple of 16; round up to 64
        size_t off = ((size_t)V * 16 + 63) & ~(size_t)63;
        corners = (uint4*)((char*)d_ws + off);

        pack_kernel<<<gridV, block, 0, stream>>>(
            voxel_centers, voxel_sizes, sdf_priors, grad_priors, vertex_indices,
            vmeta, corners, V);

        octree_sdf_h16_kernel<<<gridP, block, 0, stream>>>(
            points, voxel_indices, vmeta, corners, out_sdf, out_idx, n);
    } else {
        octree_sdf_direct_kernel<<<gridP, block, 0, stream>>>(
            points, voxel_indices, voxel_centers, vertex_indices,
            voxel_sizes, sdf_priors, grad_priors, out_sdf, out_idx, n);
    }
}

// Round 5
// 141.509 us; speedup vs baseline: 2.0222x; 1.1257x over previous
//
#include <hip/hip_runtime.h>
#include <hip/hip_fp16.h>

#define RESOLUTION 0.05f

__device__ __forceinline__ unsigned int pack_h2(float a, float b) {
    __half2 h = __floats2half2_rn(a, b);
    union { __half2 h2; unsigned int ui; } cv; cv.h2 = h;
    return cv.ui;
}
__device__ __forceinline__ float2 unpack_h2(unsigned int u) {
    union { unsigned int ui; __half2 h2; } cv; cv.ui = u;
    return __half22float2(cv.h2);
}

// ---------------- 64B per-voxel record ----------------
// [ float4 meta: cx, cy, cz, size ]
// [ 20 fp16 polynomial coeffs over basis t^i u^j v^l, packed in 10 uints ]
// coeff order: m = i + 2j + 4l for (i,j,l) in {0,1}^3           -> 0..7
//              x^2 terms (2,j,l): 8 + j + 2l                    -> 8..11
//              y^2 terms (i,2,l): 12 + i + 2l                   -> 12..15
//              z^2 terms (i,j,2): 16 + i + 2j                   -> 16..19
// sdf(t) = sum c[i][j][l] tx^i ty^j tz^l   reproduces
//   sum_k w_k(t) * (A_k + Bx_k tx + By_k ty + Bz_k tz),
//   A_k = s_k - B.bits_k, B = size*grad  (delta = size*(t - bits))

// ---------- pre-pass: build records ----------
__global__ __launch_bounds__(256) void pack_rec_kernel(
    const float* __restrict__ voxel_centers,
    const int*   __restrict__ voxel_sizes,
    const float* __restrict__ sdf_priors,
    const float* __restrict__ grad_priors,
    const int*   __restrict__ vertex_indices, // [V,8]
    uint4*       __restrict__ rec,            // [V*4] : 64B per voxel
    int V)
{
    int v = blockIdx.x * blockDim.x + threadIdx.x;
    if (v >= V) return;

    float size = (float)voxel_sizes[v] * RESOLUTION;
    float cx = voxel_centers[3*v + 0];
    float cy = voxel_centers[3*v + 1];
    float cz = voxel_centers[3*v + 2];

    const int4* vi4 = (const int4*)(vertex_indices + 8*v);
    int4 va = vi4[0];
    int4 vb = vi4[1];
    int vid[8] = {va.x, va.y, va.z, va.w, vb.x, vb.y, vb.z, vb.w};

    float c[3][3][3];
    #pragma unroll
    for (int i = 0; i < 3; ++i)
        #pragma unroll
        for (int j = 0; j < 3; ++j)
            #pragma unroll
            for (int l = 0; l < 3; ++l) c[i][j][l] = 0.0f;

    #pragma unroll
    for (int k = 0; k < 8; ++k) {
        int u = vid[k];
        float s  = sdf_priors[u];
        float Bx = size * grad_priors[3*u + 0];
        float By = size * grad_priors[3*u + 1];
        float Bz = size * grad_priors[3*u + 2];
        int bx = k & 1, by = (k >> 1) & 1, bz = (k >> 2) & 1;
        float A = s - (Bx*(float)bx + By*(float)by + Bz*(float)bz);

        // w_k = X(tx)*Y(ty)*Z(tz); X = bit ? t : 1-t  -> coeffs over t^0,t^1
        float wx[2] = { bx ? 0.0f : 1.0f, bx ? 1.0f : -1.0f };
        float wy[2] = { by ? 0.0f : 1.0f, by ? 1.0f : -1.0f };
        float wz[2] = { bz ? 0.0f : 1.0f, bz ? 1.0f : -1.0f };

        #pragma unroll
        for (int i = 0; i < 2; ++i)
            #pragma unroll
            for (int j = 0; j < 2; ++j)
                #pragma unroll
                for (int l = 0; l < 2; ++l) {
                    float wc = wx[i] * wy[j] * wz[l];
                    c[i][j][l]     += wc * A;
                    c[i+1][j][l]   += wc * Bx;
                    c[i][j+1][l]   += wc * By;
                    c[i][j][l+1]   += wc * Bz;
                }
    }

    float cf[20];
    #pragma unroll
    for (int l = 0; l < 2; ++l)
        #pragma unroll
        for (int j = 0; j < 2; ++j)
            #pragma unroll
            for (int i = 0; i < 2; ++i) cf[i + 2*j + 4*l] = c[i][j][l];
    #pragma unroll
    for (int l = 0; l < 2; ++l)
        #pragma unroll
        for (int j = 0; j < 2; ++j) {
            cf[8  + j + 2*l] = c[2][j][l];
            cf[12 + j + 2*l] = c[j][2][l];   // (i,2,l) with i=j index reuse
            cf[16 + j + 2*l] = c[j][l][2];   // (i,j,2)
        }

    union { float f; unsigned int u; } fx, fy, fz, fs;
    fx.f = cx; fy.f = cy; fz.f = cz; fs.f = size;

    uint4* out = rec + 4*v;
    out[0] = make_uint4(fx.u, fy.u, fz.u, fs.u);
    out[1] = make_uint4(pack_h2(cf[0],cf[1]),  pack_h2(cf[2],cf[3]),
                        pack_h2(cf[4],cf[5]),  pack_h2(cf[6],cf[7]));
    out[2] = make_uint4(pack_h2(cf[8],cf[9]),  pack_h2(cf[10],cf[11]),
                        pack_h2(cf[12],cf[13]),pack_h2(cf[14],cf[15]));
    out[3] = make_uint4(pack_h2(cf[16],cf[17]),pack_h2(cf[18],cf[19]), 0u, 0u);
}

// ---------- main: ONE gathered cache line per point ----------
__global__ __launch_bounds__(256) void octree_sdf_poly_kernel(
    const float* __restrict__ points,        // [P,3]
    const int*   __restrict__ voxel_indices, // [P]
    const uint4* __restrict__ rec,           // [V*4]
    float* __restrict__ out_sdf,
    float* __restrict__ out_idx,
    int n)
{
    int i = blockIdx.x * blockDim.x + threadIdx.x;
    if (i >= n) return;

    float px = points[3*i + 0];
    float py = points[3*i + 1];
    float pz = points[3*i + 2];

    int v = voxel_indices[i];

    const uint4* r = rec + 4*v;
    uint4 q0 = r[0], q1 = r[1], q2 = r[2], q3 = r[3];

    union { unsigned int u; float f; } m0, m1, m2, m3;
    m0.u = q0.x; m1.u = q0.y; m2.u = q0.z; m3.u = q0.w;
    float inv = 1.0f / m3.f;

    float tx = (px - m0.f) * inv + 0.5f;
    float ty = (py - m1.f) * inv + 0.5f;
    float tz = (pz - m2.f) * inv + 0.5f;

    float2 p01 = unpack_h2(q1.x), p23 = unpack_h2(q1.y);
    float2 p45 = unpack_h2(q1.z), p67 = unpack_h2(q1.w);
    float2 p89 = unpack_h2(q2.x), pab = unpack_h2(q2.y);
    float2 pcd = unpack_h2(q2.z), pef = unpack_h2(q2.w);
    float2 pgh = unpack_h2(q3.x), pij = unpack_h2(q3.y);

    float txty = tx * ty;
    float txtz = tx * tz;
    float tytz = ty * tz;
    float txtytz = txty * tz;

    // multilinear block: m = i + 2j + 4l
    float s = p01.x
            + p01.y * tx
            + p23.x * ty
            + p23.y * txty
            + p45.x * tz
            + p45.y * txtz
            + p67.x * tytz
            + p67.y * txtytz;
    // x^2 * {1,y,z,yz}
    float tx2 = tx * tx;
    s += tx2 * (p89.x + p89.y * ty + pab.x * tz + pab.y * tytz);
    // y^2 * {1,x,z,xz}
    float ty2 = ty * ty;
    s += ty2 * (pcd.x + pcd.y * tx + pef.x * tz + pef.y * txtz);
    // z^2 * {1,x,y,xy}
    float tz2 = tz * tz;
    s += tz2 * (pgh.x + pgh.y * tx + pij.x * ty + pij.y * txty);

    out_sdf[i] = s;
    out_idx[i] = (float)v;
}

// ---------- fallback: direct kernel (no workspace) ----------
__global__ __launch_bounds__(256) void octree_sdf_direct_kernel(
    const float* __restrict__ points,
    const int*   __restrict__ voxel_indices,
    const float* __restrict__ voxel_centers,
    const int*   __restrict__ vertex_indices,
    const int*   __restrict__ voxel_sizes,
    const float* __restrict__ sdf_priors,
    const float* __restrict__ grad_priors,
    float* __restrict__ out_sdf,
    float* __restrict__ out_idx,
    int n)
{
    int i = blockIdx.x * blockDim.x + threadIdx.x;
    if (i >= n) return;

    float px = points[3*i + 0];
    float py = points[3*i + 1];
    float pz = points[3*i + 2];

    int v = voxel_indices[i];

    float cx = voxel_centers[3*v + 0];
    float cy = voxel_centers[3*v + 1];
    float cz = voxel_centers[3*v + 2];
    float size = (float)voxel_sizes[v] * RESOLUTION;

    float tx = (px - cx) / size + 0.5f;
    float ty = (py - cy) / size + 0.5f;
    float tz = (pz - cz) / size + 0.5f;

    const int4* vi4 = (const int4*)(vertex_indices + 8*v);
    int4 va = vi4[0];
    int4 vb = vi4[1];
    int vid[8] = {va.x, va.y, va.z, va.w, vb.x, vb.y, vb.z, vb.w};

    float half_size = 0.5f * size;
    float sdf = 0.0f;

    #pragma unroll
    for (int k = 0; k < 8; ++k) {
        float bx = (float)( k       & 1);
        float by = (float)((k >> 1) & 1);
        float bz = (float)((k >> 2) & 1);

        float w = (bx > 0.0f ? tx : 1.0f - tx)
                * (by > 0.0f ? ty : 1.0f - ty)
                * (bz > 0.0f ? tz : 1.0f - tz);

        int u = vid[k];
        float val = sdf_priors[u];
        float gx  = grad_priors[3*u + 0];
        float gy  = grad_priors[3*u + 1];
        float gz  = grad_priors[3*u + 2];

        float dx = px - (cx + (2.0f*bx - 1.0f) * half_size);
        float dy = py - (cy + (2.0f*by - 1.0f) * half_size);
        float dz = pz - (cz + (2.0f*bz - 1.0f) * half_size);

        sdf += w * (val + gx*dx + gy*dy + gz*dz);
    }

    out_sdf[i] = sdf;
    out_idx[i] = (float)v;
}

extern "C" void kernel_launch(void* const* d_in, const int* in_sizes, int n_in,
                              void* d_out, int out_size, void* d_ws, size_t ws_size,
                              hipStream_t stream) {
    const float* points         = (const float*)d_in[0];
    const int*   voxel_indices  = (const int*)  d_in[1];
    const float* voxel_centers  = (const float*)d_in[2];
    const int*   vertex_indices = (const int*)  d_in[3];
    const int*   voxel_sizes    = (const int*)  d_in[4];
    const float* sdf_priors     = (const float*)d_in[5];
    const float* grad_priors    = (const float*)d_in[6];

    int n = in_sizes[1];  // points
    int V = in_sizes[4];  // voxels
    float* out_sdf = (float*)d_out;
    float* out_idx = out_sdf + n;

    int block = 256;
    int gridV = (V + block - 1) / block;
    int gridP = (n + block - 1) / block;

    size_t need = (size_t)V * 64;  // one 64B record per voxel

    if (ws_size >= need) {
        uint4* rec = (uint4*)d_ws;   // d_ws is at least 256B-aligned

        pack_rec_kernel<<<gridV, block, 0, stream>>>(
            voxel_centers, voxel_sizes, sdf_priors, grad_priors, vertex_indices,
            rec, V);

        octree_sdf_poly_kernel<<<gridP, block, 0, stream>>>(
            points, voxel_indices, rec, out_sdf, out_idx, n);
    } else {
        octree_sdf_direct_kernel<<<gridP, block, 0, stream>>>(
            points, voxel_indices, voxel_centers, vertex_indices,
            voxel_sizes, sdf_priors, grad_priors, out_sdf, out_idx, n);
    }
}